// Round 10
// baseline (400.573 us; speedup 1.0000x reference)
//
#include <hip/hip_runtime.h>

// ActionSTGCN on MI355X — round 10: r9 + tcn 128-row segments (acc 64->32
// AGPRs breaks the 128-reg/4-wave ceiling -> 5 waves/EU). T-major activations
// [b][v][t][c]; tcn block = half a (b,v) plane (128 t-outputs, 136-row
// window). Sparse adjacency mix (hardcoded BONES pattern) in pm kernels.
// Residual 1x1 folded into tcn K-steps (pre-scaled 1/i2).

typedef short bf16s;
using v8s = __attribute__((ext_vector_type(8))) short;
using v4f = __attribute__((ext_vector_type(4))) float;

#define TV 8448      // 256*33
#define NB 64
#define EPSBN 1e-5f

__device__ __forceinline__ float b2f(short s) {
  unsigned u = ((unsigned)(unsigned short)s) << 16;
  return __builtin_bit_cast(float, u);
}
__device__ __forceinline__ short f2b(float f) {
  unsigned u = __builtin_bit_cast(unsigned, f);
  u += 0x7FFFu + ((u >> 16) & 1u);   // RNE
  return (short)(u >> 16);
}

// sparsity pattern of dis@(A+I)@dis: neighbors (incl self), per output joint w
constexpr int NOFF[34] = {0,3,6,9,12,15,18,21,23,25,27,29,33,37,40,43,48,53,
                          56,59,62,65,67,69,73,77,80,83,87,91,94,97,100,103};
constexpr int NBR[103] = {
  0,1,4,    0,1,2,    1,2,3,    2,3,7,    0,4,5,    4,5,6,    5,6,8,
  3,7,      6,8,      9,10,     9,10,
  11,12,13,23,  11,12,14,24,  11,13,15,  12,14,16,
  13,15,17,19,21,  14,16,18,20,22,
  15,17,19,  16,18,20,  15,17,19,  16,18,20,  15,21,  16,22,
  11,23,24,25,  12,23,24,26,  23,25,27,  24,26,28,
  25,27,29,31,  26,28,30,32,  27,29,31,  28,30,32,  27,29,31,  28,30,32};

// ---------------- fp32 param offsets (words) --------------------------------
constexpr int P_A     = 0;        // 1089
constexpr int P_INV0  = 1089;     // 198 input-BN scale (c*33+v)
constexpr int P_BIAS0 = 1287;     // 198
constexpr int P_PB0   = 1485;     // 32
constexpr int P_PB1   = 1517;     // 64
constexpr int P_PB2   = 1581;     // 64
constexpr int P_I1_0  = 1645;  constexpr int P_B1_0 = 1677;
constexpr int P_I2_0  = 1709;  constexpr int P_B2_0 = 1741;
constexpr int P_I1_1  = 1773;  constexpr int P_B1_1 = 1837;
constexpr int P_I2_1  = 1901;  constexpr int P_B2_1 = 1965;
constexpr int P_I1_2  = 2029;  constexpr int P_B1_2 = 2093;
constexpr int P_I2_2  = 2157;  constexpr int P_B2_2 = 2221;
constexpr int P_FCW   = 2285;     // 6400
constexpr int P_FCB   = 8685;     // 100
constexpr int P_FEAT  = 8785;     // 4096 pooled sums (atomicAdd)
constexpr int P_PW0T  = 12881;    // 192 proj0 W [c*32+o]
// end 13073 words = 52292 B
constexpr size_t FRAG_OFF = 52480;           // 256-aligned
constexpr int FRS0 = 1024;    // 1*2*512   (res0: xb 8ch -> 32, NT=2)
constexpr int FCV0 = 2048;    // 9*2*512
constexpr int FPJ1 = 11264;   // 1*4*512
constexpr int FRS1 = 13312;   // 1*4*512
constexpr int FCV1 = 15360;   // 18*4*512
constexpr int FPJ2 = 52224;   // 2*4*512
constexpr int FRS2 = 56320;   // 2*4*512
constexpr int FCV2 = 60416;   // 18*4*512 -> end 97280
constexpr size_t ACT_OFF = FRAG_OFF + 97280 * 2;
constexpr size_t E64 = (size_t)NB * TV * 64;
constexpr size_t E32 = (size_t)NB * TV * 32;

// ---------------- prep ------------------------------------------------------
struct Ptrs { const float* p[48]; };

__device__ void bn1set(int tid, float* inv, float* sh, const float* g,
                       const float* b, const float* m, const float* v, int n) {
  for (int i = tid; i < n; i += 256) {
    float iv = g[i] / sqrtf(v[i] + EPSBN);
    inv[i] = iv; sh[i] = b[i] - m[i] * iv;
  }
}
__device__ void bn2set(int tid, float* inv, float* sh, const float* tb,
                       const float* g, const float* b, const float* m,
                       const float* v, const float* rb, int n) {
  for (int i = tid; i < n; i += 256) {
    float iv = g[i] / sqrtf(v[i] + EPSBN);
    inv[i] = iv;
    sh[i] = tb[i] * iv + b[i] - m[i] * iv + (rb ? rb[i] : 0.f);
  }
}

// B-frag layout: dst[(s*NT+nt)*512 + lane*8 + j] = B[k=(lane>>4)*8+j][o=nt*16+(lane&15)]
__device__ void frag_proj(int tid, short* dst, const float* W, int CIr,
                          int KS, int NT) {
  int total = KS * NT * 512;
  for (int idx = tid; idx < total; idx += 256) {
    int s = idx / (NT * 512), r = idx % (NT * 512);
    int nt = r / 512, r2 = r % 512;
    int lane = r2 >> 3, j = r2 & 7;
    int o = nt * 16 + (lane & 15);
    int ci = s * 32 + ((lane >> 4) * 8) + j;
    dst[idx] = f2b((ci < CIr) ? W[o * CIr + ci] : 0.f);
  }
}
__device__ void frag_res(int tid, short* dst, const float* W, int CIr, int ident,
                         const float* g2, const float* v2, int KS, int NT) {
  int total = KS * NT * 512;
  for (int idx = tid; idx < total; idx += 256) {
    int s = idx / (NT * 512), r = idx % (NT * 512);
    int nt = r / 512, r2 = r % 512;
    int lane = r2 >> 3, j = r2 & 7;
    int o = nt * 16 + (lane & 15);
    int ci = s * 32 + ((lane >> 4) * 8) + j;
    float val = 0.f;
    if (ident) { if (ci == o) val = 1.f; }
    else if (ci < CIr) val = W[o * CIr + ci];
    val *= sqrtf(v2[o] + EPSBN) / g2[o];   // pre-divide by bn2 scale
    dst[idx] = f2b(val);
  }
}
__device__ void frag_conv(int tid, short* dst, const float* tw, int CI, int NT) {
  int total = (CI / 32) * 9 * NT * 512;
  for (int idx = tid; idx < total; idx += 256) {
    int s = idx / (NT * 512), r = idx % (NT * 512);
    int nt = r / 512, r2 = r % 512;
    int lane = r2 >> 3, j = r2 & 7;
    int o = nt * 16 + (lane & 15);
    int kk = ((lane >> 4) * 8) + j;
    int cc = s / 9, tap = s % 9;
    int c = cc * 32 + kk;
    dst[idx] = f2b(tw[(o * CI + c) * 9 + tap]);
  }
}

__global__ __launch_bounds__(256) void prep_kernel(Ptrs in, float* __restrict__ ws,
                                                   short* __restrict__ fr) {
  const int tid = threadIdx.x;
  switch (blockIdx.x) {
    case 0: {
      for (int i = tid; i < 1089; i += 256) ws[P_A + i] = in.p[1][i];
      for (int i = tid; i < 198; i += 256) {
        float iv = in.p[2][i] / sqrtf(in.p[5][i] + EPSBN);
        ws[P_INV0 + i] = iv; ws[P_BIAS0 + i] = in.p[3][i] - in.p[4][i] * iv;
      }
      for (int i = tid; i < 32; i += 256) ws[P_PB0 + i] = in.p[7][i];
      for (int i = tid; i < 64; i += 256) { ws[P_PB1 + i] = in.p[21][i]; ws[P_PB2 + i] = in.p[35][i]; }
      bn1set(tid, ws + P_I1_0, ws + P_B1_0, in.p[8],  in.p[9],  in.p[10], in.p[11], 32);
      bn1set(tid, ws + P_I1_1, ws + P_B1_1, in.p[22], in.p[23], in.p[24], in.p[25], 64);
      bn1set(tid, ws + P_I1_2, ws + P_B1_2, in.p[36], in.p[37], in.p[38], in.p[39], 64);
      bn2set(tid, ws + P_I2_0, ws + P_B2_0, in.p[13], in.p[14], in.p[15], in.p[16], in.p[17], in.p[19], 32);
      bn2set(tid, ws + P_I2_1, ws + P_B2_1, in.p[27], in.p[28], in.p[29], in.p[30], in.p[31], in.p[33], 64);
      bn2set(tid, ws + P_I2_2, ws + P_B2_2, in.p[41], in.p[42], in.p[43], in.p[44], in.p[45], nullptr, 64);
      for (int i = tid; i < 6400; i += 256) ws[P_FCW + i] = in.p[46][i];
      for (int i = tid; i < 100; i += 256) ws[P_FCB + i] = in.p[47][i];
      for (int i = tid; i < 4096; i += 256) ws[P_FEAT + i] = 0.f;
      break;
    }
    case 1: {
      for (int i = tid; i < 192; i += 256) {
        int c = i >> 5, o = i & 31;
        ws[P_PW0T + i] = in.p[6][o * 6 + c];
      }
      break;
    }
    case 2: frag_res (tid, fr + FRS0, in.p[18], 6, 0, in.p[14], in.p[17], 1, 2); break;
    case 3: frag_conv(tid, fr + FCV0, in.p[12], 32, 2); break;
    case 4: frag_proj(tid, fr + FPJ1, in.p[20], 32, 1, 4); break;
    case 5: frag_res (tid, fr + FRS1, in.p[32], 32, 0, in.p[28], in.p[31], 1, 4); break;
    case 6: frag_conv(tid, fr + FCV1, in.p[26], 64, 4); break;
    case 7: frag_proj(tid, fr + FPJ2, in.p[34], 64, 2, 4); break;
    case 8: frag_res (tid, fr + FRS2, nullptr, 0, 1, in.p[42], in.p[45], 2, 4); break;
    case 9: frag_conv(tid, fr + FCV2, in.p[40], 64, 4); break;
  }
}

// ---------------- pm0: input BN + xb emit + sparse mix(6ch) + proj0 ---------
__global__ __launch_bounds__(256) void pm0_kern(const float* __restrict__ x,
                                                const float* __restrict__ ws,
                                                short* __restrict__ y0,
                                                short* __restrict__ xb) {
  __shared__ __align__(16) short hw[264 * 8];
  const int tid = threadIdx.x;
  const int t0 = blockIdx.x * 8, b = blockIdx.y;
  for (int i = tid; i < 264; i += 256) {
    int tt = i / 33, v = i % 33;
    int t = t0 + tt;
    v8s pack = {0,0,0,0,0,0,0,0};
#pragma unroll
    for (int c = 0; c < 6; c++) {
      float xv = x[((size_t)(b * 6 + c)) * TV + t * 33 + v];
      pack[c] = f2b(fmaf(xv, ws[P_INV0 + c * 33 + v], ws[P_BIAS0 + c * 33 + v]));
    }
    *(v8s*)(hw + (v * 8 + tt) * 8) = pack;
  }
  __syncthreads();
  for (int rr = tid; rr < 264; rr += 256) {
    int v = rr >> 3, tt = rr & 7;
    *(v8s*)(xb + (((size_t)(b * 33 + v)) * 256 + t0 + tt) * 8) =
        *(const v8s*)(hw + rr * 8);
  }
  __syncthreads();
  if (tid < 48) {
    int tt = tid / 6, c = tid % 6;
    float z[33];
#pragma unroll
    for (int v = 0; v < 33; v++) z[v] = b2f(hw[(v * 8 + tt) * 8 + c]);
#pragma unroll
    for (int w = 0; w < 33; w++) {
      float s = 0.f;
#pragma unroll
      for (int j = NOFF[w]; j < NOFF[w + 1]; j++)
        s = fmaf(ws[P_A + w * 33 + NBR[j]], z[NBR[j]], s);
      hw[(w * 8 + tt) * 8 + c] = f2b(s);
    }
  }
  __syncthreads();
  for (int rr = tid; rr < 264; rr += 256) {
    int v = rr >> 3, tt = rr & 7;
    float hv[6];
#pragma unroll
    for (int c = 0; c < 6; c++) hv[c] = b2f(hw[rr * 8 + c]);
    float acc[32];
#pragma unroll
    for (int o = 0; o < 32; o++) acc[o] = ws[P_PB0 + o];
#pragma unroll
    for (int c = 0; c < 6; c++)
#pragma unroll
      for (int o = 0; o < 32; o++) acc[o] = fmaf(hv[c], ws[P_PW0T + c * 32 + o], acc[o]);
    short* dst = y0 + (((size_t)(b * 33 + v)) * 256 + t0 + tt) * 32;
#pragma unroll
    for (int u = 0; u < 4; u++) {
      v8s t;
#pragma unroll
      for (int j = 0; j < 8; j++) {
        int o = u * 8 + j;
        t[j] = f2b(fmaxf(fmaf(acc[o], ws[P_I1_0 + o], ws[P_B1_0 + o]), 0.f));
      }
      *(v8s*)(dst + u * 8) = t;
    }
  }
}

// ---------------- pm: sparse mix(CI) + 1x1 proj MFMA (+bn1relu) -> y --------
template <int CI>
__global__ __launch_bounds__(256, 4) void pm_kern(const short* __restrict__ in,
                                                  const short* __restrict__ fpj,
                                                  const float* __restrict__ ws,
                                                  short* __restrict__ y,
                                                  int pbO, int i1O, int b1O) {
  constexpr int KS = CI / 32;
  constexpr int RSI = CI + 8;
  constexpr int CH = CI / 8;
  __shared__ __align__(16) short hw[264 * RSI];
  const int tid = threadIdx.x;
  const int t0 = blockIdx.x * 8, b = blockIdx.y;
  const int lane = tid & 63, wv = tid >> 6;
  const int ln = lane & 15, q8 = (lane >> 4) * 8;

  const v8s* pf = (const v8s*)fpj;
  v8s bf[KS][4];
#pragma unroll
  for (int ks = 0; ks < KS; ks++)
#pragma unroll
    for (int nt = 0; nt < 4; nt++) bf[ks][nt] = pf[(ks * 4 + nt) * 64 + lane];

  for (int u = tid; u < 264 * CH; u += 256) {
    int v = u / (8 * CH), r = u % (8 * CH);
    int tt = r / CH, c0 = (r % CH) * 8;
    *(v8s*)(hw + (v * 8 + tt) * RSI + c0) =
        *(const v8s*)(in + (((size_t)(b * 33 + v)) * 256 + t0 + tt) * CI + c0);
  }
  __syncthreads();

  // sparse mix in place (slot = (tt, oc); hardcoded adjacency pattern)
  for (int u = tid; u < 8 * CI; u += 256) {
    int tt = u / CI, oc = u % CI;
    float z[33];
#pragma unroll
    for (int v = 0; v < 33; v++) z[v] = b2f(hw[(v * 8 + tt) * RSI + oc]);
#pragma unroll
    for (int w = 0; w < 33; w++) {
      float s = 0.f;
#pragma unroll
      for (int j = NOFF[w]; j < NOFF[w + 1]; j++)
        s = fmaf(ws[P_A + w * 33 + NBR[j]], z[NBR[j]], s);
      hw[(w * 8 + tt) * RSI + oc] = f2b(s);
    }
  }
  __syncthreads();

  for (int i = 0; i < 5; i++) {
    int tile = wv + 4 * i;
    if (tile < 17) {
      int arow = tile * 16 + ln;
      v8s afr[KS];
#pragma unroll
      for (int ks = 0; ks < KS; ks++) {
        v8s zv = {0,0,0,0,0,0,0,0};
        afr[ks] = (arow < 264) ? *(const v8s*)(hw + arow * RSI + ks * 32 + q8) : zv;
      }
      v4f d[4];
#pragma unroll
      for (int nt = 0; nt < 4; nt++) d[nt] = (v4f){0.f, 0.f, 0.f, 0.f};
#pragma unroll
      for (int ks = 0; ks < KS; ks++)
#pragma unroll
        for (int nt = 0; nt < 4; nt++)
          d[nt] = __builtin_amdgcn_mfma_f32_16x16x32_bf16(afr[ks], bf[ks][nt], d[nt], 0, 0, 0);
#pragma unroll
      for (int nt = 0; nt < 4; nt++) {
        int o = nt * 16 + ln;
        float i1 = ws[i1O + o];
        float sh = fmaf(ws[pbO + o], i1, ws[b1O + o]);
#pragma unroll
        for (int r = 0; r < 4; r++) {
          int rr = tile * 16 + (lane >> 4) * 4 + r;
          if (rr < 264) {
            int v = rr >> 3, tt = rr & 7;
            y[(((size_t)(b * 33 + v)) * 256 + t0 + tt) * 64 + o] =
                f2b(fmaxf(fmaf(d[nt][r], i1, sh), 0.f));
          }
        }
      }
    }
  }
}

// ---------------- tcn: temporal conv GEMM + folded residual -----------------
// Block = HALF a (b,v) joint plane: 128 t-outputs, window 136 rows. acc is
// 2mt x NT (32 AGPR at CO=64) -> combined regs ~96 -> 5 waves/EU achievable.
// grid (33, NB, 2); seg = blockIdx.z. RMODE 0: res = xb 8ch co-staged.
// 1: res 32ch restage. 2: identity 64ch restage. POOL: fused avg-pool.
template <int CI, int CO, int RMODE, bool POOL>
__global__ __launch_bounds__(256, 4) void tcn_kern(
    const short* __restrict__ y, const short* __restrict__ res,
    const short* __restrict__ fcv, const short* __restrict__ frs,
    const float* __restrict__ ws, short* __restrict__ out,
    float* __restrict__ feat, int i2O, int b2O) {
  constexpr int NT = CO / 16;
  constexpr int RSI = CI + 8;
  constexpr int CH = CI / 8;
  constexpr int S = (CI / 32) * 9;
  constexpr int WIN = 136;
  constexpr int RESOFF = WIN * RSI;
  constexpr int LDSZ = (RMODE == 0) ? (WIN * RSI + 132 * 8) : (WIN * RSI);
  __shared__ __align__(16) short win[LDSZ];
  const int tid = threadIdx.x;
  const int v = blockIdx.x, b = blockIdx.y;
  const int t0 = blockIdx.z * 128;
  const int lane = tid & 63, wv = tid >> 6;
  const int ln = lane & 15, q8 = (lane >> 4) * 8;
  const int wvbase = wv * 32;                 // 2 m-tiles (32 rows) per wave
  const v8s* cf = (const v8s*)fcv;
  const v8s* rf = (const v8s*)frs;
  const size_t plane = ((size_t)(b * 33 + v)) * 256;

  v8s bcur[NT];
#pragma unroll
  for (int nt = 0; nt < NT; nt++) bcur[nt] = cf[nt * 64 + lane];

  const short* src = y + plane * CI;
  for (int u = tid; u < WIN * CH; u += 256) {
    int r = u / CH, c0 = (u % CH) * 8;
    int t = t0 + r - 4;
    v8s val = {0,0,0,0,0,0,0,0};
    if (t >= 0 && t < 256) val = *(const v8s*)(src + (size_t)t * CI + c0);
    *(v8s*)(win + r * RSI + c0) = val;
  }
  if constexpr (RMODE == 0) {
    for (int u = tid; u < 132; u += 256) {
      v8s val = {0,0,0,0,0,0,0,0};
      if (u < 128) val = *(const v8s*)(res + (plane + t0 + u) * 8);
      *(v8s*)(win + RESOFF + u * 8) = val;
    }
  }
  __syncthreads();

  v4f acc[2][NT];
#pragma unroll
  for (int mt = 0; mt < 2; mt++)
#pragma unroll
    for (int nt = 0; nt < NT; nt++) acc[mt][nt] = (v4f){0.f, 0.f, 0.f, 0.f};

  for (int s = 0; s < S; s++) {
    int cc = s / 9, tap = s % 9;
    v8s bnx[NT];
    if (s + 1 < S) {
#pragma unroll
      for (int nt = 0; nt < NT; nt++) bnx[nt] = cf[((s + 1) * NT + nt) * 64 + lane];
    }
    v8s afr[2];
#pragma unroll
    for (int mt = 0; mt < 2; mt++) {
      int row = wvbase + mt * 16 + ln + tap;
      afr[mt] = *(const v8s*)(win + row * RSI + cc * 32 + q8);
    }
#pragma unroll
    for (int mt = 0; mt < 2; mt++)
#pragma unroll
      for (int nt = 0; nt < NT; nt++)
        acc[mt][nt] = __builtin_amdgcn_mfma_f32_16x16x32_bf16(
            afr[mt], bcur[nt], acc[mt][nt], 0, 0, 0);
    if (s + 1 < S) {
#pragma unroll
      for (int nt = 0; nt < NT; nt++) bcur[nt] = bnx[nt];
    }
  }

  if constexpr (RMODE == 0) {
    v8s rb[NT];
#pragma unroll
    for (int nt = 0; nt < NT; nt++) rb[nt] = rf[nt * 64 + lane];
    v8s afr[2];
#pragma unroll
    for (int mt = 0; mt < 2; mt++) {
      int row = wvbase + mt * 16 + ln;
      afr[mt] = *(const v8s*)(win + RESOFF + row * 8 + q8);  // q8>0 lanes: B=0
    }
#pragma unroll
    for (int mt = 0; mt < 2; mt++)
#pragma unroll
      for (int nt = 0; nt < NT; nt++)
        acc[mt][nt] = __builtin_amdgcn_mfma_f32_16x16x32_bf16(
            afr[mt], rb[nt], acc[mt][nt], 0, 0, 0);
  } else {
    constexpr int RKS = (RMODE == 2) ? 2 : 1;
    __syncthreads();
    constexpr int RCH = (RMODE == 2) ? 8 : 4;
    for (int u = tid; u < 128 * RCH; u += 256) {
      int r = u / RCH, c0 = (u % RCH) * 8;
      *(v8s*)(win + r * RSI + c0) =
          *(const v8s*)(res + (plane + t0 + r) * (RKS * 32) + c0);
    }
    __syncthreads();
#pragma unroll
    for (int ks = 0; ks < RKS; ks++) {
      v8s rb[NT];
#pragma unroll
      for (int nt = 0; nt < NT; nt++) rb[nt] = rf[(ks * NT + nt) * 64 + lane];
      v8s afr[2];
#pragma unroll
      for (int mt = 0; mt < 2; mt++) {
        int row = wvbase + mt * 16 + ln;
        afr[mt] = *(const v8s*)(win + row * RSI + ks * 32 + q8);
      }
#pragma unroll
      for (int mt = 0; mt < 2; mt++)
#pragma unroll
        for (int nt = 0; nt < NT; nt++)
          acc[mt][nt] = __builtin_amdgcn_mfma_f32_16x16x32_bf16(
              afr[mt], rb[nt], acc[mt][nt], 0, 0, 0);
    }
  }

  if constexpr (POOL) {
    float ps[NT];
#pragma unroll
    for (int nt = 0; nt < NT; nt++) {
      int o = nt * 16 + ln;
      float sA = ws[i2O + o], sB = ws[b2O + o];
      float sl = 0.f;
#pragma unroll
      for (int mt = 0; mt < 2; mt++)
#pragma unroll
        for (int r = 0; r < 4; r++)
          sl += fmaxf(fmaf(acc[mt][nt][r], sA, sB), 0.f);
      ps[nt] = sl;
    }
#pragma unroll
    for (int nt = 0; nt < NT; nt++) {
      ps[nt] += __shfl_xor(ps[nt], 16);
      ps[nt] += __shfl_xor(ps[nt], 32);
    }
    __syncthreads();
    float* pl = (float*)win;
    if (lane < 16) {
#pragma unroll
      for (int nt = 0; nt < NT; nt++) pl[wv * 64 + nt * 16 + lane] = ps[nt];
    }
    __syncthreads();
    if (tid < 64)
      atomicAdd(&feat[b * 64 + tid],
                pl[tid] + pl[64 + tid] + pl[128 + tid] + pl[192 + tid]);
  } else {
#pragma unroll
    for (int nt = 0; nt < NT; nt++) {
      int o = nt * 16 + ln;
      float sA = ws[i2O + o], sB = ws[b2O + o];
#pragma unroll
      for (int mt = 0; mt < 2; mt++)
#pragma unroll
        for (int r = 0; r < 4; r++) {
          int t = t0 + wvbase + mt * 16 + (lane >> 4) * 4 + r;
          float val = fmaxf(fmaf(acc[mt][nt][r], sA, sB), 0.f);
          out[(plane + t) * CO + o] = f2b(val);
        }
    }
  }
}

// ---------------- k4: FC ----------------------------------------------------
__global__ __launch_bounds__(128) void k4_kern(const float* __restrict__ ws,
                                               float* __restrict__ out) {
  const int b = blockIdx.x, tid = threadIdx.x;
  __shared__ float sf[64];
  if (tid < 64) sf[tid] = ws[P_FEAT + b * 64 + tid] * (1.f / 8448.f);
  __syncthreads();
  if (tid < 100) {
    float a = ws[P_FCB + tid];
#pragma unroll
    for (int o = 0; o < 64; o++) a = fmaf(ws[P_FCW + tid * 64 + o], sf[o], a);
    out[b * 100 + tid] = a;
  }
}

// ---------------- launch -----------------------------------------------------
extern "C" void kernel_launch(void* const* d_in, const int* in_sizes, int n_in,
                              void* d_out, int out_size, void* d_ws, size_t ws_size,
                              hipStream_t stream) {
  const float* xin = (const float*)d_in[0];
  float* wsf = (float*)d_ws;
  char* wsb = (char*)d_ws;
  short* frags = (short*)(wsb + FRAG_OFF);
  short* RA = (short*)(wsb + ACT_OFF);       // 64ch: y1, then y2
  short* RB = RA + E64;                      // y0+xb, later h1
  short* RC = RB + E64;                      // h0 (32ch)
  short* y0 = RB;
  short* xb = RB + E32;
  short* h0 = RC;
  short* y1 = RA;
  short* h1 = RB;
  short* y2 = RA;
  float* feat = wsf + P_FEAT;

  Ptrs ptrs;
  for (int i = 0; i < 48 && i < n_in; i++) ptrs.p[i] = (const float*)d_in[i];

  prep_kernel<<<10, 256, 0, stream>>>(ptrs, wsf, frags);

  dim3 gpm(32, NB), gtc(33, NB, 2);
  pm0_kern<<<gpm, 256, 0, stream>>>(xin, wsf, y0, xb);
  tcn_kern<32, 32, 0, false><<<gtc, 256, 0, stream>>>(
      y0, xb, frags + FCV0, frags + FRS0, wsf, h0, nullptr, P_I2_0, P_B2_0);
  pm_kern<32><<<gpm, 256, 0, stream>>>(h0, frags + FPJ1, wsf, y1, P_PB1, P_I1_1, P_B1_1);
  tcn_kern<64, 64, 1, false><<<gtc, 256, 0, stream>>>(
      y1, h0, frags + FCV1, frags + FRS1, wsf, h1, nullptr, P_I2_1, P_B2_1);
  pm_kern<64><<<gpm, 256, 0, stream>>>(h1, frags + FPJ2, wsf, y2, P_PB2, P_I1_2, P_B1_2);
  tcn_kern<64, 64, 2, true><<<gtc, 256, 0, stream>>>(
      y2, h1, frags + FCV2, frags + FRS2, wsf, nullptr, feat, P_I2_2, P_B2_2);
  k4_kern<<<NB, 128, 0, stream>>>(wsf, (float*)d_out);
}

// Round 11
// 375.460 us; speedup vs baseline: 1.0669x; 1.0669x over previous
//
#include <hip/hip_runtime.h>

// ActionSTGCN on MI355X — round 11: r9 tcn (4 m-tiles, full plane) +
// cooperative per-step B-fragment staging into double-buffered LDS via
// global_load_lds (cuts 4x-duplicated B VMEM traffic), and direct-global
// residual A-frags for RMODE 1/2 (no restage, no extra barriers).
// T-major activations [b][v][t][c]; sparse adjacency mix in pm kernels.

typedef short bf16s;
using v8s = __attribute__((ext_vector_type(8))) short;
using v4f = __attribute__((ext_vector_type(4))) float;

#define TV 8448      // 256*33
#define NB 64
#define EPSBN 1e-5f

__device__ __forceinline__ float b2f(short s) {
  unsigned u = ((unsigned)(unsigned short)s) << 16;
  return __builtin_bit_cast(float, u);
}
__device__ __forceinline__ short f2b(float f) {
  unsigned u = __builtin_bit_cast(unsigned, f);
  u += 0x7FFFu + ((u >> 16) & 1u);   // RNE
  return (short)(u >> 16);
}
__device__ __forceinline__ void gll16(const void* g, void* l) {
  __builtin_amdgcn_global_load_lds(
      (const __attribute__((address_space(1))) void*)g,
      (__attribute__((address_space(3))) void*)l, 16, 0, 0);
}

// sparsity pattern of dis@(A+I)@dis: neighbors (incl self), per output joint w
constexpr int NOFF[34] = {0,3,6,9,12,15,18,21,23,25,27,29,33,37,40,43,48,53,
                          56,59,62,65,67,69,73,77,80,83,87,91,94,97,100,103};
constexpr int NBR[103] = {
  0,1,4,    0,1,2,    1,2,3,    2,3,7,    0,4,5,    4,5,6,    5,6,8,
  3,7,      6,8,      9,10,     9,10,
  11,12,13,23,  11,12,14,24,  11,13,15,  12,14,16,
  13,15,17,19,21,  14,16,18,20,22,
  15,17,19,  16,18,20,  15,17,19,  16,18,20,  15,21,  16,22,
  11,23,24,25,  12,23,24,26,  23,25,27,  24,26,28,
  25,27,29,31,  26,28,30,32,  27,29,31,  28,30,32,  27,29,31,  28,30,32};

// ---------------- fp32 param offsets (words) --------------------------------
constexpr int P_A     = 0;        // 1089
constexpr int P_INV0  = 1089;     // 198 input-BN scale (c*33+v)
constexpr int P_BIAS0 = 1287;     // 198
constexpr int P_PB0   = 1485;     // 32
constexpr int P_PB1   = 1517;     // 64
constexpr int P_PB2   = 1581;     // 64
constexpr int P_I1_0  = 1645;  constexpr int P_B1_0 = 1677;
constexpr int P_I2_0  = 1709;  constexpr int P_B2_0 = 1741;
constexpr int P_I1_1  = 1773;  constexpr int P_B1_1 = 1837;
constexpr int P_I2_1  = 1901;  constexpr int P_B2_1 = 1965;
constexpr int P_I1_2  = 2029;  constexpr int P_B1_2 = 2093;
constexpr int P_I2_2  = 2157;  constexpr int P_B2_2 = 2221;
constexpr int P_FCW   = 2285;     // 6400
constexpr int P_FCB   = 8685;     // 100
constexpr int P_FEAT  = 8785;     // 4096 pooled sums (atomicAdd)
constexpr int P_PW0T  = 12881;    // 192 proj0 W [c*32+o]
// end 13073 words = 52292 B
constexpr size_t FRAG_OFF = 52480;           // 256-aligned
constexpr int FRS0 = 1024;    // 1*2*512   (res0: xb 8ch -> 32, NT=2)
constexpr int FCV0 = 2048;    // 9*2*512
constexpr int FPJ1 = 11264;   // 1*4*512
constexpr int FRS1 = 13312;   // 1*4*512
constexpr int FCV1 = 15360;   // 18*4*512
constexpr int FPJ2 = 52224;   // 2*4*512
constexpr int FRS2 = 56320;   // 2*4*512
constexpr int FCV2 = 60416;   // 18*4*512 -> end 97280
constexpr size_t ACT_OFF = FRAG_OFF + 97280 * 2;
constexpr size_t E64 = (size_t)NB * TV * 64;
constexpr size_t E32 = (size_t)NB * TV * 32;

// ---------------- prep ------------------------------------------------------
struct Ptrs { const float* p[48]; };

__device__ void bn1set(int tid, float* inv, float* sh, const float* g,
                       const float* b, const float* m, const float* v, int n) {
  for (int i = tid; i < n; i += 256) {
    float iv = g[i] / sqrtf(v[i] + EPSBN);
    inv[i] = iv; sh[i] = b[i] - m[i] * iv;
  }
}
__device__ void bn2set(int tid, float* inv, float* sh, const float* tb,
                       const float* g, const float* b, const float* m,
                       const float* v, const float* rb, int n) {
  for (int i = tid; i < n; i += 256) {
    float iv = g[i] / sqrtf(v[i] + EPSBN);
    inv[i] = iv;
    sh[i] = tb[i] * iv + b[i] - m[i] * iv + (rb ? rb[i] : 0.f);
  }
}

// B-frag layout: dst[(s*NT+nt)*512 + lane*8 + j] = B[k=(lane>>4)*8+j][o=nt*16+(lane&15)]
__device__ void frag_proj(int tid, short* dst, const float* W, int CIr,
                          int KS, int NT) {
  int total = KS * NT * 512;
  for (int idx = tid; idx < total; idx += 256) {
    int s = idx / (NT * 512), r = idx % (NT * 512);
    int nt = r / 512, r2 = r % 512;
    int lane = r2 >> 3, j = r2 & 7;
    int o = nt * 16 + (lane & 15);
    int ci = s * 32 + ((lane >> 4) * 8) + j;
    dst[idx] = f2b((ci < CIr) ? W[o * CIr + ci] : 0.f);
  }
}
__device__ void frag_res(int tid, short* dst, const float* W, int CIr, int ident,
                         const float* g2, const float* v2, int KS, int NT) {
  int total = KS * NT * 512;
  for (int idx = tid; idx < total; idx += 256) {
    int s = idx / (NT * 512), r = idx % (NT * 512);
    int nt = r / 512, r2 = r % 512;
    int lane = r2 >> 3, j = r2 & 7;
    int o = nt * 16 + (lane & 15);
    int ci = s * 32 + ((lane >> 4) * 8) + j;
    float val = 0.f;
    if (ident) { if (ci == o) val = 1.f; }
    else if (ci < CIr) val = W[o * CIr + ci];
    val *= sqrtf(v2[o] + EPSBN) / g2[o];   // pre-divide by bn2 scale
    dst[idx] = f2b(val);
  }
}
__device__ void frag_conv(int tid, short* dst, const float* tw, int CI, int NT) {
  int total = (CI / 32) * 9 * NT * 512;
  for (int idx = tid; idx < total; idx += 256) {
    int s = idx / (NT * 512), r = idx % (NT * 512);
    int nt = r / 512, r2 = r % 512;
    int lane = r2 >> 3, j = r2 & 7;
    int o = nt * 16 + (lane & 15);
    int kk = ((lane >> 4) * 8) + j;
    int cc = s / 9, tap = s % 9;
    int c = cc * 32 + kk;
    dst[idx] = f2b(tw[(o * CI + c) * 9 + tap]);
  }
}

__global__ __launch_bounds__(256) void prep_kernel(Ptrs in, float* __restrict__ ws,
                                                   short* __restrict__ fr) {
  const int tid = threadIdx.x;
  switch (blockIdx.x) {
    case 0: {
      for (int i = tid; i < 1089; i += 256) ws[P_A + i] = in.p[1][i];
      for (int i = tid; i < 198; i += 256) {
        float iv = in.p[2][i] / sqrtf(in.p[5][i] + EPSBN);
        ws[P_INV0 + i] = iv; ws[P_BIAS0 + i] = in.p[3][i] - in.p[4][i] * iv;
      }
      for (int i = tid; i < 32; i += 256) ws[P_PB0 + i] = in.p[7][i];
      for (int i = tid; i < 64; i += 256) { ws[P_PB1 + i] = in.p[21][i]; ws[P_PB2 + i] = in.p[35][i]; }
      bn1set(tid, ws + P_I1_0, ws + P_B1_0, in.p[8],  in.p[9],  in.p[10], in.p[11], 32);
      bn1set(tid, ws + P_I1_1, ws + P_B1_1, in.p[22], in.p[23], in.p[24], in.p[25], 64);
      bn1set(tid, ws + P_I1_2, ws + P_B1_2, in.p[36], in.p[37], in.p[38], in.p[39], 64);
      bn2set(tid, ws + P_I2_0, ws + P_B2_0, in.p[13], in.p[14], in.p[15], in.p[16], in.p[17], in.p[19], 32);
      bn2set(tid, ws + P_I2_1, ws + P_B2_1, in.p[27], in.p[28], in.p[29], in.p[30], in.p[31], in.p[33], 64);
      bn2set(tid, ws + P_I2_2, ws + P_B2_2, in.p[41], in.p[42], in.p[43], in.p[44], in.p[45], nullptr, 64);
      for (int i = tid; i < 6400; i += 256) ws[P_FCW + i] = in.p[46][i];
      for (int i = tid; i < 100; i += 256) ws[P_FCB + i] = in.p[47][i];
      for (int i = tid; i < 4096; i += 256) ws[P_FEAT + i] = 0.f;
      break;
    }
    case 1: {
      for (int i = tid; i < 192; i += 256) {
        int c = i >> 5, o = i & 31;
        ws[P_PW0T + i] = in.p[6][o * 6 + c];
      }
      break;
    }
    case 2: frag_res (tid, fr + FRS0, in.p[18], 6, 0, in.p[14], in.p[17], 1, 2); break;
    case 3: frag_conv(tid, fr + FCV0, in.p[12], 32, 2); break;
    case 4: frag_proj(tid, fr + FPJ1, in.p[20], 32, 1, 4); break;
    case 5: frag_res (tid, fr + FRS1, in.p[32], 32, 0, in.p[28], in.p[31], 1, 4); break;
    case 6: frag_conv(tid, fr + FCV1, in.p[26], 64, 4); break;
    case 7: frag_proj(tid, fr + FPJ2, in.p[34], 64, 2, 4); break;
    case 8: frag_res (tid, fr + FRS2, nullptr, 0, 1, in.p[42], in.p[45], 2, 4); break;
    case 9: frag_conv(tid, fr + FCV2, in.p[40], 64, 4); break;
  }
}

// ---------------- pm0: input BN + xb emit + sparse mix(6ch) + proj0 ---------
__global__ __launch_bounds__(256) void pm0_kern(const float* __restrict__ x,
                                                const float* __restrict__ ws,
                                                short* __restrict__ y0,
                                                short* __restrict__ xb) {
  __shared__ __align__(16) short hw[264 * 8];
  const int tid = threadIdx.x;
  const int t0 = blockIdx.x * 8, b = blockIdx.y;
  for (int i = tid; i < 264; i += 256) {
    int tt = i / 33, v = i % 33;
    int t = t0 + tt;
    v8s pack = {0,0,0,0,0,0,0,0};
#pragma unroll
    for (int c = 0; c < 6; c++) {
      float xv = x[((size_t)(b * 6 + c)) * TV + t * 33 + v];
      pack[c] = f2b(fmaf(xv, ws[P_INV0 + c * 33 + v], ws[P_BIAS0 + c * 33 + v]));
    }
    *(v8s*)(hw + (v * 8 + tt) * 8) = pack;
  }
  __syncthreads();
  for (int rr = tid; rr < 264; rr += 256) {
    int v = rr >> 3, tt = rr & 7;
    *(v8s*)(xb + (((size_t)(b * 33 + v)) * 256 + t0 + tt) * 8) =
        *(const v8s*)(hw + rr * 8);
  }
  __syncthreads();
  if (tid < 48) {
    int tt = tid / 6, c = tid % 6;
    float z[33];
#pragma unroll
    for (int v = 0; v < 33; v++) z[v] = b2f(hw[(v * 8 + tt) * 8 + c]);
#pragma unroll
    for (int w = 0; w < 33; w++) {
      float s = 0.f;
#pragma unroll
      for (int j = NOFF[w]; j < NOFF[w + 1]; j++)
        s = fmaf(ws[P_A + w * 33 + NBR[j]], z[NBR[j]], s);
      hw[(w * 8 + tt) * 8 + c] = f2b(s);
    }
  }
  __syncthreads();
  for (int rr = tid; rr < 264; rr += 256) {
    int v = rr >> 3, tt = rr & 7;
    float hv[6];
#pragma unroll
    for (int c = 0; c < 6; c++) hv[c] = b2f(hw[rr * 8 + c]);
    float acc[32];
#pragma unroll
    for (int o = 0; o < 32; o++) acc[o] = ws[P_PB0 + o];
#pragma unroll
    for (int c = 0; c < 6; c++)
#pragma unroll
      for (int o = 0; o < 32; o++) acc[o] = fmaf(hv[c], ws[P_PW0T + c * 32 + o], acc[o]);
    short* dst = y0 + (((size_t)(b * 33 + v)) * 256 + t0 + tt) * 32;
#pragma unroll
    for (int u = 0; u < 4; u++) {
      v8s t;
#pragma unroll
      for (int j = 0; j < 8; j++) {
        int o = u * 8 + j;
        t[j] = f2b(fmaxf(fmaf(acc[o], ws[P_I1_0 + o], ws[P_B1_0 + o]), 0.f));
      }
      *(v8s*)(dst + u * 8) = t;
    }
  }
}

// ---------------- pm: sparse mix(CI) + 1x1 proj MFMA (+bn1relu) -> y --------
template <int CI>
__global__ __launch_bounds__(256, 4) void pm_kern(const short* __restrict__ in,
                                                  const short* __restrict__ fpj,
                                                  const float* __restrict__ ws,
                                                  short* __restrict__ y,
                                                  int pbO, int i1O, int b1O) {
  constexpr int KS = CI / 32;
  constexpr int RSI = CI + 8;
  constexpr int CH = CI / 8;
  __shared__ __align__(16) short hw[264 * RSI];
  const int tid = threadIdx.x;
  const int t0 = blockIdx.x * 8, b = blockIdx.y;
  const int lane = tid & 63, wv = tid >> 6;
  const int ln = lane & 15, q8 = (lane >> 4) * 8;

  const v8s* pf = (const v8s*)fpj;
  v8s bf[KS][4];
#pragma unroll
  for (int ks = 0; ks < KS; ks++)
#pragma unroll
    for (int nt = 0; nt < 4; nt++) bf[ks][nt] = pf[(ks * 4 + nt) * 64 + lane];

  for (int u = tid; u < 264 * CH; u += 256) {
    int v = u / (8 * CH), r = u % (8 * CH);
    int tt = r / CH, c0 = (r % CH) * 8;
    *(v8s*)(hw + (v * 8 + tt) * RSI + c0) =
        *(const v8s*)(in + (((size_t)(b * 33 + v)) * 256 + t0 + tt) * CI + c0);
  }
  __syncthreads();

  // sparse mix in place (slot = (tt, oc); hardcoded adjacency pattern)
  for (int u = tid; u < 8 * CI; u += 256) {
    int tt = u / CI, oc = u % CI;
    float z[33];
#pragma unroll
    for (int v = 0; v < 33; v++) z[v] = b2f(hw[(v * 8 + tt) * RSI + oc]);
#pragma unroll
    for (int w = 0; w < 33; w++) {
      float s = 0.f;
#pragma unroll
      for (int j = NOFF[w]; j < NOFF[w + 1]; j++)
        s = fmaf(ws[P_A + w * 33 + NBR[j]], z[NBR[j]], s);
      hw[(w * 8 + tt) * RSI + oc] = f2b(s);
    }
  }
  __syncthreads();

  for (int i = 0; i < 5; i++) {
    int tile = wv + 4 * i;
    if (tile < 17) {
      int arow = tile * 16 + ln;
      v8s afr[KS];
#pragma unroll
      for (int ks = 0; ks < KS; ks++) {
        v8s zv = {0,0,0,0,0,0,0,0};
        afr[ks] = (arow < 264) ? *(const v8s*)(hw + arow * RSI + ks * 32 + q8) : zv;
      }
      v4f d[4];
#pragma unroll
      for (int nt = 0; nt < 4; nt++) d[nt] = (v4f){0.f, 0.f, 0.f, 0.f};
#pragma unroll
      for (int ks = 0; ks < KS; ks++)
#pragma unroll
        for (int nt = 0; nt < 4; nt++)
          d[nt] = __builtin_amdgcn_mfma_f32_16x16x32_bf16(afr[ks], bf[ks][nt], d[nt], 0, 0, 0);
#pragma unroll
      for (int nt = 0; nt < 4; nt++) {
        int o = nt * 16 + ln;
        float i1 = ws[i1O + o];
        float sh = fmaf(ws[pbO + o], i1, ws[b1O + o]);
#pragma unroll
        for (int r = 0; r < 4; r++) {
          int rr = tile * 16 + (lane >> 4) * 4 + r;
          if (rr < 264) {
            int v = rr >> 3, tt = rr & 7;
            y[(((size_t)(b * 33 + v)) * 256 + t0 + tt) * 64 + o] =
                f2b(fmaxf(fmaf(d[nt][r], i1, sh), 0.f));
          }
        }
      }
    }
  }
}

// ---------------- tcn: temporal conv GEMM + folded residual -----------------
// Block = one (b,v) plane: 256 t-outputs, 264-row window. B-fragments staged
// per-step into double-buffered LDS cooperatively (global_load_lds), one
// barrier per step. RMODE 0: res = xb 8ch co-staged (LDS). RMODE 1/2:
// residual A-frags direct from global (no restage, no barriers).
template <int CI, int CO, int RMODE, bool POOL>
__global__ __launch_bounds__(256, 4) void tcn_kern(
    const short* __restrict__ y, const short* __restrict__ res,
    const short* __restrict__ fcv, const short* __restrict__ frs,
    const float* __restrict__ ws, short* __restrict__ out,
    float* __restrict__ feat, int i2O, int b2O) {
  constexpr int NT = CO / 16;
  constexpr int RSI = CI + 8;
  constexpr int CH = CI / 8;
  constexpr int S = (CI / 32) * 9;
  constexpr int RESOFF = 264 * RSI;
  constexpr int BOFF = (RMODE == 0) ? (RESOFF + 2080) : RESOFF;  // B dbuf (shorts)
  constexpr int BSTEP = NT * 512;                                // shorts per buffer
  constexpr int LDSZ = BOFF + 2 * BSTEP;
  __shared__ __align__(16) short win[LDSZ];
  const int tid = threadIdx.x;
  const int v = blockIdx.x, b = blockIdx.y;
  const int lane = tid & 63, wv = tid >> 6;
  const int ln = lane & 15, q8 = (lane >> 4) * 8;
  const int wvbase = wv * 64;
  const v8s* rf = (const v8s*)frs;
  const size_t plane = ((size_t)(b * 33 + v)) * 256;
  short* bstage = win + BOFF;

  // prologue: issue B-frag load for step 0 (wave w stages its quarter)
  if (NT == 4 || wv < 2)
    gll16(fcv + ((size_t)wv * 64 + lane) * 8, bstage + wv * 512);

  const short* src = y + plane * CI;
  for (int u = tid; u < 264 * CH; u += 256) {
    int r = u / CH, c0 = (u % CH) * 8;
    int t = r - 4;
    v8s val = {0,0,0,0,0,0,0,0};
    if (t >= 0 && t < 256) val = *(const v8s*)(src + (size_t)t * CI + c0);
    *(v8s*)(win + r * RSI + c0) = val;
  }
  if constexpr (RMODE == 0) {
    for (int u = tid; u < 260; u += 256) {
      v8s val = {0,0,0,0,0,0,0,0};
      if (u < 256) val = *(const v8s*)(res + (plane + u) * 8);
      *(v8s*)(win + RESOFF + u * 8) = val;
    }
  }
  __syncthreads();   // drains window stores + step-0 B load

  v4f acc[4][NT];
#pragma unroll
  for (int mt = 0; mt < 4; mt++)
#pragma unroll
    for (int nt = 0; nt < NT; nt++) acc[mt][nt] = (v4f){0.f, 0.f, 0.f, 0.f};

  for (int s = 0; s < S; s++) {
    int cc = s / 9, tap = s % 9;
    // issue next step's B-frag staging (lands before next barrier's drain)
    if (s + 1 < S && (NT == 4 || wv < 2))
      gll16(fcv + ((size_t)(s + 1) * NT * 64 + wv * 64 + lane) * 8,
            bstage + ((s + 1) & 1) * BSTEP + wv * 512);
    v8s bfr[NT];
#pragma unroll
    for (int nt = 0; nt < NT; nt++)
      bfr[nt] = *(const v8s*)(bstage + (s & 1) * BSTEP + (nt * 64 + lane) * 8);
    v8s afr[4];
#pragma unroll
    for (int mt = 0; mt < 4; mt++) {
      int row = wvbase + mt * 16 + ln + tap;
      afr[mt] = *(const v8s*)(win + row * RSI + cc * 32 + q8);
    }
#pragma unroll
    for (int mt = 0; mt < 4; mt++)
#pragma unroll
      for (int nt = 0; nt < NT; nt++)
        acc[mt][nt] = __builtin_amdgcn_mfma_f32_16x16x32_bf16(
            afr[mt], bfr[nt], acc[mt][nt], 0, 0, 0);
    __syncthreads();   // step boundary: cur reads done; next B-buf complete
  }

  // residual K-steps
  if constexpr (RMODE == 0) {
    v8s rb[NT];
#pragma unroll
    for (int nt = 0; nt < NT; nt++) rb[nt] = rf[nt * 64 + lane];
    v8s afr[4];
#pragma unroll
    for (int mt = 0; mt < 4; mt++) {
      int row = wvbase + mt * 16 + ln;
      afr[mt] = *(const v8s*)(win + RESOFF + row * 8 + q8);  // q8>0 lanes: B=0
    }
#pragma unroll
    for (int mt = 0; mt < 4; mt++)
#pragma unroll
      for (int nt = 0; nt < NT; nt++)
        acc[mt][nt] = __builtin_amdgcn_mfma_f32_16x16x32_bf16(
            afr[mt], rb[nt], acc[mt][nt], 0, 0, 0);
  } else {
    constexpr int RKS = (RMODE == 2) ? 2 : 1;
    constexpr int RST = RKS * 32;
#pragma unroll
    for (int ks = 0; ks < RKS; ks++) {
      v8s rb[NT];
#pragma unroll
      for (int nt = 0; nt < NT; nt++) rb[nt] = rf[(ks * NT + nt) * 64 + lane];
      v8s afr[4];
#pragma unroll
      for (int mt = 0; mt < 4; mt++) {
        int row = wvbase + mt * 16 + ln;
        afr[mt] = *(const v8s*)(res + (plane + row) * RST + ks * 32 + q8);
      }
#pragma unroll
      for (int mt = 0; mt < 4; mt++)
#pragma unroll
        for (int nt = 0; nt < NT; nt++)
          acc[mt][nt] = __builtin_amdgcn_mfma_f32_16x16x32_bf16(
              afr[mt], rb[nt], acc[mt][nt], 0, 0, 0);
    }
  }

  // epilogue: bn2 + relu (residual pre-scaled into acc)
  if constexpr (POOL) {
    float ps[NT];
#pragma unroll
    for (int nt = 0; nt < NT; nt++) {
      int o = nt * 16 + ln;
      float sA = ws[i2O + o], sB = ws[b2O + o];
      float sl = 0.f;
#pragma unroll
      for (int mt = 0; mt < 4; mt++)
#pragma unroll
        for (int r = 0; r < 4; r++)
          sl += fmaxf(fmaf(acc[mt][nt][r], sA, sB), 0.f);
      ps[nt] = sl;
    }
#pragma unroll
    for (int nt = 0; nt < NT; nt++) {
      ps[nt] += __shfl_xor(ps[nt], 16);
      ps[nt] += __shfl_xor(ps[nt], 32);
    }
    __syncthreads();
    float* pl = (float*)win;
    if (lane < 16) {
#pragma unroll
      for (int nt = 0; nt < NT; nt++) pl[wv * 64 + nt * 16 + lane] = ps[nt];
    }
    __syncthreads();
    if (tid < 64)
      atomicAdd(&feat[b * 64 + tid],
                pl[tid] + pl[64 + tid] + pl[128 + tid] + pl[192 + tid]);
  } else {
#pragma unroll
    for (int nt = 0; nt < NT; nt++) {
      int o = nt * 16 + ln;
      float sA = ws[i2O + o], sB = ws[b2O + o];
#pragma unroll
      for (int mt = 0; mt < 4; mt++)
#pragma unroll
        for (int r = 0; r < 4; r++) {
          int t = wvbase + mt * 16 + (lane >> 4) * 4 + r;
          float val = fmaxf(fmaf(acc[mt][nt][r], sA, sB), 0.f);
          out[(plane + t) * CO + o] = f2b(val);
        }
    }
  }
}

// ---------------- k4: FC ----------------------------------------------------
__global__ __launch_bounds__(128) void k4_kern(const float* __restrict__ ws,
                                               float* __restrict__ out) {
  const int b = blockIdx.x, tid = threadIdx.x;
  __shared__ float sf[64];
  if (tid < 64) sf[tid] = ws[P_FEAT + b * 64 + tid] * (1.f / 8448.f);
  __syncthreads();
  if (tid < 100) {
    float a = ws[P_FCB + tid];
#pragma unroll
    for (int o = 0; o < 64; o++) a = fmaf(ws[P_FCW + tid * 64 + o], sf[o], a);
    out[b * 100 + tid] = a;
  }
}

// ---------------- launch -----------------------------------------------------
extern "C" void kernel_launch(void* const* d_in, const int* in_sizes, int n_in,
                              void* d_out, int out_size, void* d_ws, size_t ws_size,
                              hipStream_t stream) {
  const float* xin = (const float*)d_in[0];
  float* wsf = (float*)d_ws;
  char* wsb = (char*)d_ws;
  short* frags = (short*)(wsb + FRAG_OFF);
  short* RA = (short*)(wsb + ACT_OFF);       // 64ch: y1, then y2
  short* RB = RA + E64;                      // y0+xb, later h1
  short* RC = RB + E64;                      // h0 (32ch)
  short* y0 = RB;
  short* xb = RB + E32;
  short* h0 = RC;
  short* y1 = RA;
  short* h1 = RB;
  short* y2 = RA;
  float* feat = wsf + P_FEAT;

  Ptrs ptrs;
  for (int i = 0; i < 48 && i < n_in; i++) ptrs.p[i] = (const float*)d_in[i];

  prep_kernel<<<10, 256, 0, stream>>>(ptrs, wsf, frags);

  dim3 gpm(32, NB), gtc(33, NB);
  pm0_kern<<<gpm, 256, 0, stream>>>(xin, wsf, y0, xb);
  tcn_kern<32, 32, 0, false><<<gtc, 256, 0, stream>>>(
      y0, xb, frags + FCV0, frags + FRS0, wsf, h0, nullptr, P_I2_0, P_B2_0);
  pm_kern<32><<<gpm, 256, 0, stream>>>(h0, frags + FPJ1, wsf, y1, P_PB1, P_I1_1, P_B1_1);
  tcn_kern<64, 64, 1, false><<<gtc, 256, 0, stream>>>(
      y1, h0, frags + FCV1, frags + FRS1, wsf, h1, nullptr, P_I2_1, P_B2_1);
  pm_kern<64><<<gpm, 256, 0, stream>>>(h1, frags + FPJ2, wsf, y2, P_PB2, P_I1_2, P_B1_2);
  tcn_kern<64, 64, 2, true><<<gtc, 256, 0, stream>>>(
      y2, h1, frags + FCV2, frags + FRS2, wsf, nullptr, feat, P_I2_2, P_B2_2);
  k4_kern<<<NB, 128, 0, stream>>>(wsf, (float*)d_out);
}